// Round 8
// baseline (97.904 us; speedup 1.0000x reference)
//
#include <hip/hip_runtime.h>

typedef __bf16 bf16x8 __attribute__((ext_vector_type(8)));
typedef float f32x4 __attribute__((ext_vector_type(4)));

#define DEV static __device__ __forceinline__

DEV unsigned short f2b(float f){
    unsigned int u = __float_as_uint(f);
    u += 0x7fffu + ((u >> 16) & 1u);
    return (unsigned short)(u >> 16);
}
DEV float b2f(unsigned short h){ return __uint_as_float(((unsigned int)h) << 16); }
DEV float gelu_f(float x){ return 0.5f * x * (1.0f + erff(x * 0.7071067811865476f)); }

// async global->LDS, 16B per lane. LDS dest MUST be wave-uniform; HW scatters
// base + lane*16. Passing a uniform base avoids any backend waterfall on a
// divergent LDS pointer.
DEV void gload16(const unsigned short* g, unsigned short* l){
    __builtin_amdgcn_global_load_lds(
        (const __attribute__((address_space(1))) void*)g,
        (__attribute__((address_space(3))) void*)l, 16, 0, 0);
}

// ---------------------------------------------------------------- constants
static constexpr int NROW = 8192;   // B*D*H*W = 2*16*16*16
static constexpr int C    = 256;
static constexpr int F    = 1024;
static constexpr float ATT_SCALE = 0.17677669529663688f;   // 1/sqrt(32)

// ---------------------------------------------------------------- prep + LN1
// Blocks 0..191: LDS-tiled transpose+bf16 of the 6 weight mats (64x64 tiles,
// coalesced reads AND writes). Block 192: [bq*s|bk|bv]. Blocks 193+: LN1.
__global__ __launch_bounds__(256)
void prep_ln_kernel(const float* __restrict__ Wq, const float* __restrict__ Wk,
                    const float* __restrict__ Wv, const float* __restrict__ Wo,
                    const float* __restrict__ W1, const float* __restrict__ W2,
                    const float* __restrict__ bq, const float* __restrict__ bk,
                    const float* __restrict__ bv,
                    unsigned short* __restrict__ WQT, unsigned short* __restrict__ WKT,
                    unsigned short* __restrict__ WVT, unsigned short* __restrict__ WOT,
                    unsigned short* __restrict__ W1T, unsigned short* __restrict__ W2T,
                    float* __restrict__ bqkv,
                    const float* __restrict__ x, const float* __restrict__ g1,
                    const float* __restrict__ b1,
                    unsigned short* __restrict__ tn, unsigned short* __restrict__ xb)
{
    const int tid = threadIdx.x;
    if (blockIdx.x < 192) {
        __shared__ unsigned short T[64][66];
        const int t = blockIdx.x;
        const float* src; unsigned short* dst;
        int ldw, ldt, r0, c0; float sc = 1.0f;
        if (t < 64) {                       // 4 square 256x256 mats, 16 tiles each
            const int m = t >> 4, sub = t & 15;
            src = (m == 0) ? Wq : (m == 1) ? Wk : (m == 2) ? Wv : Wo;
            dst = (m == 0) ? WQT : (m == 1) ? WKT : (m == 2) ? WVT : WOT;
            if (m == 0) sc = ATT_SCALE;
            ldw = 256; ldt = 256;
            r0 = (sub >> 2) * 64; c0 = (sub & 3) * 64;
        } else if (t < 128) {               // W1: 256x1024 -> W1T [1024][256]
            const int sub = t - 64;
            src = W1; dst = W1T; ldw = 1024; ldt = 256;
            r0 = (sub >> 4) * 64; c0 = (sub & 15) * 64;
        } else {                            // W2: 1024x256 -> W2T [256][1024]
            const int sub = t - 128;
            src = W2; dst = W2T; ldw = 256; ldt = 1024;
            r0 = (sub >> 2) * 64; c0 = (sub & 3) * 64;
        }
        #pragma unroll
        for (int i = 0; i < 16; ++i) {
            const int rl = i * 4 + (tid >> 6), cl = tid & 63;
            T[rl][cl] = f2b(src[(size_t)(r0 + rl) * ldw + c0 + cl] * sc);
        }
        __syncthreads();
        #pragma unroll
        for (int j = 0; j < 16; ++j) {
            const int cl = j * 4 + (tid >> 6), rl = tid & 63;
            dst[(size_t)(c0 + cl) * ldt + r0 + rl] = T[rl][cl];
        }
    } else if (blockIdx.x == 192) {
        #pragma unroll
        for (int i = 0; i < 3; ++i) {
            const int v = i * 256 + tid;
            bqkv[v] = (v < 256) ? bq[v] * ATT_SCALE
                    : (v < 512) ? bk[v - 256] : bv[v - 512];
        }
    } else {
        const int row  = (blockIdx.x - 193) * 4 + (tid >> 6);
        const int lane = tid & 63;
        float4 v = ((const float4*)(x + (size_t)row * C))[lane];
        float s = v.x + v.y + v.z + v.w;
        #pragma unroll
        for (int m = 32; m >= 1; m >>= 1) s += __shfl_xor(s, m);
        const float mean = s * (1.0f / 256.0f);
        const float d0 = v.x - mean, d1 = v.y - mean, d2 = v.z - mean, d3 = v.w - mean;
        float s2 = d0 * d0 + d1 * d1 + d2 * d2 + d3 * d3;
        #pragma unroll
        for (int m = 32; m >= 1; m >>= 1) s2 += __shfl_xor(s2, m);
        const float rstd = rsqrtf(s2 * (1.0f / 256.0f) + 1e-5f);
        float4 gg = ((const float4*)g1)[lane];
        float4 bb = ((const float4*)b1)[lane];
        ushort4 o = { f2b(d0 * rstd * gg.x + bb.x), f2b(d1 * rstd * gg.y + bb.y),
                      f2b(d2 * rstd * gg.z + bb.z), f2b(d3 * rstd * gg.w + bb.w) };
        ((ushort4*)(tn + (size_t)row * C))[lane] = o;
        ushort4 xo = { f2b(v.x), f2b(v.y), f2b(v.z), f2b(v.w) };
        ((ushort4*)(xb + (size_t)row * C))[lane] = xo;
    }
}

// ---------------------------------------------------------------- LN2
__global__ __launch_bounds__(256)
void ln_kernel(const float* __restrict__ X, const float* __restrict__ g,
               const float* __restrict__ bta, unsigned short* __restrict__ OUT)
{
    const int row  = blockIdx.x * 4 + (threadIdx.x >> 6);
    const int lane = threadIdx.x & 63;
    float4 v = ((const float4*)(X + (size_t)row * C))[lane];
    float s = v.x + v.y + v.z + v.w;
    #pragma unroll
    for (int m = 32; m >= 1; m >>= 1) s += __shfl_xor(s, m);
    const float mean = s * (1.0f / 256.0f);
    const float d0 = v.x - mean, d1 = v.y - mean, d2 = v.z - mean, d3 = v.w - mean;
    float s2 = d0 * d0 + d1 * d1 + d2 * d2 + d3 * d3;
    #pragma unroll
    for (int m = 32; m >= 1; m >>= 1) s2 += __shfl_xor(s2, m);
    const float rstd = rsqrtf(s2 * (1.0f / 256.0f) + 1e-5f);
    float4 gg = ((const float4*)g)[lane];
    float4 bb = ((const float4*)bta)[lane];
    ushort4 o = { f2b(d0 * rstd * gg.x + bb.x), f2b(d1 * rstd * gg.y + bb.y),
                  f2b(d2 * rstd * gg.z + bb.z), f2b(d3 * rstd * gg.w + bb.w) };
    ((ushort4*)(OUT + (size_t)row * C))[lane] = o;
}

// ---------------------------------------------------------------- 64x64 GEMM
// BK=64, 4 waves, dbuf LDS via gload_lds w16 (WAVE-UNIFORM LDS base),
// XOR swizzle (rule #21): inverse-swizzled global src chunk + swizzled ds_read.
// LDS layout: elem(row, c16) = row*64 + (c16 ^ (row&7))*8.
template<int K, int MODE>
DEV void gemm_body(const unsigned short* __restrict__ A, int m0,
                   const unsigned short* __restrict__ BTt,
                   const float* __restrict__ biast,
                   const float* __restrict__ res, void* __restrict__ outp,
                   int ldo, int ocol0,
                   unsigned short (&As)[2][4096], unsigned short (&Bs)[2][4096])
{
    constexpr int BK = 64, NKT = K / BK;
    const int tid  = threadIdx.x;
    const int lane = tid & 63, wid = tid >> 6;
    const int srow = tid >> 3;                    // 0..31
    const int schk = (tid & 7) ^ (srow & 7);      // inverse-swizzled src chunk

    const unsigned short* Ag = A   + (size_t)(m0 + srow) * K + schk * 8;
    const unsigned short* Bg = BTt + (size_t)srow        * K + schk * 8;

    // wave-uniform LDS element base: wave w covers [w*512, w*512+512)
    const int wbase = __builtin_amdgcn_readfirstlane(wid) * 512;

    gload16(Ag,          &As[0][wbase]);
    gload16(Ag + 32 * K, &As[0][wbase + 2048]);
    gload16(Bg,          &Bs[0][wbase]);
    gload16(Bg + 32 * K, &Bs[0][wbase + 2048]);
    __syncthreads();

    f32x4 acc[4] = {};
    const int lr = lane & 15, lk = lane >> 4;
    const int sw = lr & 7;

    for (int kt = 0; kt < NKT; ++kt) {
        if (kt + 1 < NKT) {
            const int nb = (kt + 1) & 1;
            gload16(Ag + (kt + 1) * BK,          &As[nb][wbase]);
            gload16(Ag + 32 * K + (kt + 1) * BK, &As[nb][wbase + 2048]);
            gload16(Bg + (kt + 1) * BK,          &Bs[nb][wbase]);
            gload16(Bg + 32 * K + (kt + 1) * BK, &Bs[nb][wbase + 2048]);
        }
        const unsigned short* as = As[kt & 1];
        const unsigned short* bs = Bs[kt & 1];
        #pragma unroll
        for (int s = 0; s < 2; ++s) {
            const int c16 = (s * 4 + lk) ^ sw;
            bf16x8 bfr = *reinterpret_cast<const bf16x8*>(&bs[(wid * 16 + lr) * 64 + c16 * 8]);
            #pragma unroll
            for (int m = 0; m < 4; ++m) {
                bf16x8 afr = *reinterpret_cast<const bf16x8*>(&as[(m * 16 + lr) * 64 + c16 * 8]);
                acc[m] = __builtin_amdgcn_mfma_f32_16x16x32_bf16(afr, bfr, acc[m], 0, 0, 0);
            }
        }
        if (kt + 1 < NKT) __syncthreads();
    }

    const int col  = ocol0 + wid * 16 + lr;
    const float bcol = biast[wid * 16 + lr];
    #pragma unroll
    for (int m = 0; m < 4; ++m) {
        #pragma unroll
        for (int r = 0; r < 4; ++r) {
            const int row = m0 + m * 16 + lk * 4 + r;
            float v = acc[m][r] + bcol;
            if (MODE == 0) {
                ((unsigned short*)outp)[(size_t)row * ldo + col] = f2b(v);
            } else if (MODE == 1) {
                ((unsigned short*)outp)[(size_t)row * ldo + col] = f2b(gelu_f(v));
            } else {
                v += res[(size_t)row * ldo + col];
                ((float*)outp)[(size_t)row * ldo + col] = v;
            }
        }
    }
}

// XCD-swizzled 1D-grid tile map, column-fastest (T1). Requires nwg % 8 == 0.
template<int NC, int TS>
DEV void tile_map(int& m0, int& n0){
    const int nwg = gridDim.x;
    const int lin = blockIdx.x;
    const int tile = (lin & 7) * (nwg >> 3) + (lin >> 3);
    m0 = (tile / NC) * TS;
    n0 = (tile % NC) * TS;
}

// Fused Q/K/V GEMM: N=768 packed output, A = tn for Q cols, xb for K/V cols.
__global__ __launch_bounds__(256)
void qkv_kernel(const unsigned short* __restrict__ tn,
                const unsigned short* __restrict__ xb,
                const unsigned short* __restrict__ WT,    // [768][256]
                const float* __restrict__ bqkv,           // [768]
                unsigned short* __restrict__ QKV)         // [8192][768]
{
    __shared__ unsigned short As[2][4096], Bs[2][4096];
    int m0, n0; tile_map<12, 64>(m0, n0);
    const unsigned short* A = (n0 < 256) ? tn : xb;
    gemm_body<256, 0>(A, m0, WT + (size_t)n0 * 256,
                      bqkv + n0, nullptr, QKV, 768, n0, As, Bs);
}

template<int K, int MODE, int NC>
__global__ __launch_bounds__(256)
void gemm_kernel(const unsigned short* __restrict__ A,
                 const unsigned short* __restrict__ BT,
                 const float* __restrict__ bias,
                 const float* __restrict__ res,
                 void* __restrict__ outp, int ldo)
{
    __shared__ unsigned short As[2][4096], Bs[2][4096];
    int m0, n0; tile_map<NC, 64>(m0, n0);
    gemm_body<K, MODE>(A, m0, BT + (size_t)n0 * K,
                       bias + n0, res, outp, ldo, n0, As, Bs);
}

// ---------------------------------------------------------------- attention
// 2 voxels per THREAD via the batch axis: (b=0,d,h,w) and (b=1,d,h,w) share
// the validity mask (wave-uniform) and all index math; 2x independent
// load/FMA streams hide gather latency. 4 voxel-pairs per 256-thread block.
// Thread = 4 contiguous channels of one head: lane l -> head l>>3, chans (l&7)*4.
// QKV layout: [NROW][768] bf16: Q (pre-scaled) 0..255, K 256..511, V 512..767.
__global__ __launch_bounds__(256)
void attn_kernel(const unsigned short* __restrict__ QKV,
                 unsigned short* __restrict__ AO)
{
    const int vp = blockIdx.x * 4 + (threadIdx.x >> 6);   // 0..4095 = (d,h,w)
    const int l  = threadIdx.x & 63;
    const int d = vp >> 8, h = (vp >> 4) & 15, w = vp & 15;
    const int ch = (l >> 3) * 32 + (l & 7) * 4;

    ushort4 qa = *reinterpret_cast<const ushort4*>(&QKV[(size_t)vp * 768 + ch]);
    ushort4 qb = *reinterpret_cast<const ushort4*>(&QKV[(size_t)(vp + 4096) * 768 + ch]);
    const float a0 = b2f(qa.x), a1 = b2f(qa.y), a2 = b2f(qa.z), a3 = b2f(qa.w);
    const float c0 = b2f(qb.x), c1 = b2f(qb.y), c2 = b2f(qb.z), c3 = b2f(qb.w);

    float s0[27], s1[27];
    int   nrow[27];
    #pragma unroll
    for (int kk = 0; kk < 27; ++kk) {
        const int di = kk / 9 - 1, hi = (kk / 3) % 3 - 1, wi = kk % 3 - 1;
        int nd = d + di, nh = h + hi, nw = w + wi;
        bool valid = (kk != 13) && ((unsigned)nd < 16u) && ((unsigned)nh < 16u) && ((unsigned)nw < 16u);
        if (valid) {
            const int r = (nd << 8) + (nh << 4) + nw;
            nrow[kk] = r;
            ushort4 k0 = *reinterpret_cast<const ushort4*>(&QKV[(size_t)r * 768 + 256 + ch]);
            ushort4 k1 = *reinterpret_cast<const ushort4*>(&QKV[(size_t)(r + 4096) * 768 + 256 + ch]);
            float t0 = a0 * b2f(k0.x) + a1 * b2f(k0.y) + a2 * b2f(k0.z) + a3 * b2f(k0.w);
            float t1 = c0 * b2f(k1.x) + c1 * b2f(k1.y) + c2 * b2f(k1.z) + c3 * b2f(k1.w);
            t0 += __shfl_xor(t0, 4);  t1 += __shfl_xor(t1, 4);
            t0 += __shfl_xor(t0, 2);  t1 += __shfl_xor(t1, 2);
            t0 += __shfl_xor(t0, 1);  t1 += __shfl_xor(t1, 1);
            s0[kk] = t0; s1[kk] = t1;
        } else {
            s0[kk] = -INFINITY; s1[kk] = -INFINITY;
            nrow[kk] = -1;
        }
    }

    float m0 = -INFINITY, m1 = -INFINITY;
    #pragma unroll
    for (int kk = 0; kk < 27; ++kk) { m0 = fmaxf(m0, s0[kk]); m1 = fmaxf(m1, s1[kk]); }
    float z0 = 0.0f, z1 = 0.0f;
    #pragma unroll
    for (int kk = 0; kk < 27; ++kk) {
        float p0 = __expf(s0[kk] - m0); s0[kk] = p0; z0 += p0;
        float p1 = __expf(s1[kk] - m1); s1[kk] = p1; z1 += p1;
    }
    const float i0 = 1.0f / z0, i1 = 1.0f / z1;

    float o00 = 0.f, o01 = 0.f, o02 = 0.f, o03 = 0.f;
    float o10 = 0.f, o11 = 0.f, o12 = 0.f, o13 = 0.f;
    #pragma unroll
    for (int kk = 0; kk < 27; ++kk) {
        if (nrow[kk] >= 0) {
            const int r = nrow[kk];
            ushort4 v0 = *reinterpret_cast<const ushort4*>(&QKV[(size_t)r * 768 + 512 + ch]);
            ushort4 v1 = *reinterpret_cast<const ushort4*>(&QKV[(size_t)(r + 4096) * 768 + 512 + ch]);
            const float p0 = s0[kk], p1 = s1[kk];
            o00 += p0 * b2f(v0.x); o01 += p0 * b2f(v0.y);
            o02 += p0 * b2f(v0.z); o03 += p0 * b2f(v0.w);
            o10 += p1 * b2f(v1.x); o11 += p1 * b2f(v1.y);
            o12 += p1 * b2f(v1.z); o13 += p1 * b2f(v1.w);
        }
    }
    ushort4 w0 = { f2b(o00 * i0), f2b(o01 * i0), f2b(o02 * i0), f2b(o03 * i0) };
    ushort4 w1 = { f2b(o10 * i1), f2b(o11 * i1), f2b(o12 * i1), f2b(o13 * i1) };
    *reinterpret_cast<ushort4*>(&AO[(size_t)vp * C + ch]) = w0;
    *reinterpret_cast<ushort4*>(&AO[(size_t)(vp + 4096) * C + ch]) = w1;
}

// ---------------------------------------------------------------- launch
extern "C" void kernel_launch(void* const* d_in, const int* in_sizes, int n_in,
                              void* d_out, int out_size, void* d_ws, size_t ws_size,
                              hipStream_t stream)
{
    const float* x   = (const float*)d_in[0];
    const float* Wq  = (const float*)d_in[1];
    const float* bq  = (const float*)d_in[2];
    const float* Wk  = (const float*)d_in[3];
    const float* bk  = (const float*)d_in[4];
    const float* Wv  = (const float*)d_in[5];
    const float* bv  = (const float*)d_in[6];
    const float* Wo  = (const float*)d_in[7];
    const float* bo  = (const float*)d_in[8];
    const float* g1  = (const float*)d_in[9];
    const float* b1  = (const float*)d_in[10];
    const float* g2  = (const float*)d_in[11];
    const float* b2  = (const float*)d_in[12];
    const float* W1  = (const float*)d_in[13];
    const float* bf1 = (const float*)d_in[14];
    const float* W2  = (const float*)d_in[15];
    const float* bf2 = (const float*)d_in[16];

    char* ws = (char*)d_ws;
    size_t o = 0;
    unsigned short* WQT = (unsigned short*)(ws + o); o += (size_t)256 * 256 * 2;   // [768][256] with WKT/WVT
    unsigned short* WKT = (unsigned short*)(ws + o); o += (size_t)256 * 256 * 2;
    unsigned short* WVT = (unsigned short*)(ws + o); o += (size_t)256 * 256 * 2;
    unsigned short* WOT = (unsigned short*)(ws + o); o += (size_t)256 * 256 * 2;
    unsigned short* W1T = (unsigned short*)(ws + o); o += (size_t)256 * 1024 * 2;
    unsigned short* W2T = (unsigned short*)(ws + o); o += (size_t)1024 * 256 * 2;
    float*          bqkv= (float*)(ws + o);          o += (size_t)768 * 4;
    unsigned short* tn  = (unsigned short*)(ws + o); o += (size_t)NROW * C * 2;
    unsigned short* xb  = (unsigned short*)(ws + o); o += (size_t)NROW * C * 2;
    unsigned short* QKVb= (unsigned short*)(ws + o); o += (size_t)NROW * 768 * 2;
    unsigned short* AOb = (unsigned short*)(ws + o); o += (size_t)NROW * C * 2;
    float*          Tf  = (float*)(ws + o);          o += (size_t)NROW * C * 4;
    unsigned short* tn2 = (unsigned short*)(ws + o); o += (size_t)NROW * C * 2;
    unsigned short* Hb  = (unsigned short*)(ws + o); o += (size_t)NROW * F * 2;

    prep_ln_kernel<<<193 + NROW / 4, 256, 0, stream>>>(Wq, Wk, Wv, Wo, W1, W2, bq, bk, bv,
                                                       WQT, WKT, WVT, WOT, W1T, W2T, bqkv,
                                                       x, g1, b1, tn, xb);

    qkv_kernel<<<(NROW / 64) * 12, 256, 0, stream>>>(tn, xb, WQT, bqkv, QKVb);

    attn_kernel<<<1024, 256, 0, stream>>>(QKVb, AOb);

    gemm_kernel<256, 2, 4><<<(NROW / 64) * 4, 256, 0, stream>>>(AOb, WOT, bo, x, Tf, 256);

    ln_kernel<<<NROW / 4, 256, 0, stream>>>(Tf, g2, b2, tn2);

    gemm_kernel<256, 1, 16><<<(NROW / 64) * 16, 256, 0, stream>>>(tn2, W1T, bf1, nullptr, Hb, 1024);

    gemm_kernel<1024, 2, 4><<<(NROW / 64) * 4, 256, 0, stream>>>(Hb, W2T, bf2, Tf, (float*)d_out, 256);
}

// Round 9
// 76.887 us; speedup vs baseline: 1.2733x; 1.2733x over previous
//
#include <hip/hip_runtime.h>

typedef __bf16 bf16x8 __attribute__((ext_vector_type(8)));
typedef float f32x4 __attribute__((ext_vector_type(4)));

#define DEV static __device__ __forceinline__

DEV unsigned short f2b(float f){
    unsigned int u = __float_as_uint(f);
    u += 0x7fffu + ((u >> 16) & 1u);
    return (unsigned short)(u >> 16);
}
DEV float b2f(unsigned short h){ return __uint_as_float(((unsigned int)h) << 16); }
DEV float blo(unsigned int u){ return __uint_as_float(u << 16); }
DEV float bhi(unsigned int u){ return __uint_as_float(u & 0xffff0000u); }
DEV float gelu_f(float x){ return 0.5f * x * (1.0f + erff(x * 0.7071067811865476f)); }

// async global->LDS, 16B per lane, wave-uniform LDS base (HW adds lane*16).
DEV void gload16(const unsigned short* g, unsigned short* l){
    __builtin_amdgcn_global_load_lds(
        (const __attribute__((address_space(1))) void*)g,
        (__attribute__((address_space(3))) void*)l, 16, 0, 0);
}

// ---------------------------------------------------------------- constants
static constexpr int NROW = 8192;   // B*D*H*W = 2*16*16*16
static constexpr int C    = 256;
static constexpr int F    = 1024;
static constexpr float ATT_SCALE = 0.17677669529663688f;   // 1/sqrt(32)

// ---------------------------------------------------------------- prep + LN1
__global__ __launch_bounds__(256)
void prep_ln_kernel(const float* __restrict__ Wq, const float* __restrict__ Wk,
                    const float* __restrict__ Wv, const float* __restrict__ Wo,
                    const float* __restrict__ W1, const float* __restrict__ W2,
                    const float* __restrict__ bq, const float* __restrict__ bk,
                    const float* __restrict__ bv,
                    unsigned short* __restrict__ WQT, unsigned short* __restrict__ WKT,
                    unsigned short* __restrict__ WVT, unsigned short* __restrict__ WOT,
                    unsigned short* __restrict__ W1T, unsigned short* __restrict__ W2T,
                    float* __restrict__ bqkv,
                    const float* __restrict__ x, const float* __restrict__ g1,
                    const float* __restrict__ b1,
                    unsigned short* __restrict__ tn, unsigned short* __restrict__ xb)
{
    const int tid = threadIdx.x;
    if (blockIdx.x < 192) {
        __shared__ unsigned short T[64][66];
        const int t = blockIdx.x;
        const float* src; unsigned short* dst;
        int ldw, ldt, r0, c0; float sc = 1.0f;
        if (t < 64) {                       // 4 square 256x256 mats, 16 tiles each
            const int m = t >> 4, sub = t & 15;
            src = (m == 0) ? Wq : (m == 1) ? Wk : (m == 2) ? Wv : Wo;
            dst = (m == 0) ? WQT : (m == 1) ? WKT : (m == 2) ? WVT : WOT;
            if (m == 0) sc = ATT_SCALE;
            ldw = 256; ldt = 256;
            r0 = (sub >> 2) * 64; c0 = (sub & 3) * 64;
        } else if (t < 128) {               // W1: 256x1024 -> W1T [1024][256]
            const int sub = t - 64;
            src = W1; dst = W1T; ldw = 1024; ldt = 256;
            r0 = (sub >> 4) * 64; c0 = (sub & 15) * 64;
        } else {                            // W2: 1024x256 -> W2T [256][1024]
            const int sub = t - 128;
            src = W2; dst = W2T; ldw = 256; ldt = 1024;
            r0 = (sub >> 2) * 64; c0 = (sub & 3) * 64;
        }
        #pragma unroll
        for (int i = 0; i < 16; ++i) {
            const int rl = i * 4 + (tid >> 6), cl = tid & 63;
            T[rl][cl] = f2b(src[(size_t)(r0 + rl) * ldw + c0 + cl] * sc);
        }
        __syncthreads();
        #pragma unroll
        for (int j = 0; j < 16; ++j) {
            const int cl = j * 4 + (tid >> 6), rl = tid & 63;
            dst[(size_t)(c0 + cl) * ldt + r0 + rl] = T[rl][cl];
        }
    } else if (blockIdx.x == 192) {
        #pragma unroll
        for (int i = 0; i < 3; ++i) {
            const int v = i * 256 + tid;
            bqkv[v] = (v < 256) ? bq[v] * ATT_SCALE
                    : (v < 512) ? bk[v - 256] : bv[v - 512];
        }
    } else {
        const int row  = (blockIdx.x - 193) * 4 + (tid >> 6);
        const int lane = tid & 63;
        float4 v = ((const float4*)(x + (size_t)row * C))[lane];
        float s = v.x + v.y + v.z + v.w;
        #pragma unroll
        for (int m = 32; m >= 1; m >>= 1) s += __shfl_xor(s, m);
        const float mean = s * (1.0f / 256.0f);
        const float d0 = v.x - mean, d1 = v.y - mean, d2 = v.z - mean, d3 = v.w - mean;
        float s2 = d0 * d0 + d1 * d1 + d2 * d2 + d3 * d3;
        #pragma unroll
        for (int m = 32; m >= 1; m >>= 1) s2 += __shfl_xor(s2, m);
        const float rstd = rsqrtf(s2 * (1.0f / 256.0f) + 1e-5f);
        float4 gg = ((const float4*)g1)[lane];
        float4 bb = ((const float4*)b1)[lane];
        ushort4 o = { f2b(d0 * rstd * gg.x + bb.x), f2b(d1 * rstd * gg.y + bb.y),
                      f2b(d2 * rstd * gg.z + bb.z), f2b(d3 * rstd * gg.w + bb.w) };
        ((ushort4*)(tn + (size_t)row * C))[lane] = o;
        ushort4 xo = { f2b(v.x), f2b(v.y), f2b(v.z), f2b(v.w) };
        ((ushort4*)(xb + (size_t)row * C))[lane] = xo;
    }
}

// ---------------------------------------------------------------- LN2
__global__ __launch_bounds__(256)
void ln_kernel(const float* __restrict__ X, const float* __restrict__ g,
               const float* __restrict__ bta, unsigned short* __restrict__ OUT)
{
    const int row  = blockIdx.x * 4 + (threadIdx.x >> 6);
    const int lane = threadIdx.x & 63;
    float4 v = ((const float4*)(X + (size_t)row * C))[lane];
    float s = v.x + v.y + v.z + v.w;
    #pragma unroll
    for (int m = 32; m >= 1; m >>= 1) s += __shfl_xor(s, m);
    const float mean = s * (1.0f / 256.0f);
    const float d0 = v.x - mean, d1 = v.y - mean, d2 = v.z - mean, d3 = v.w - mean;
    float s2 = d0 * d0 + d1 * d1 + d2 * d2 + d3 * d3;
    #pragma unroll
    for (int m = 32; m >= 1; m >>= 1) s2 += __shfl_xor(s2, m);
    const float rstd = rsqrtf(s2 * (1.0f / 256.0f) + 1e-5f);
    float4 gg = ((const float4*)g)[lane];
    float4 bb = ((const float4*)bta)[lane];
    ushort4 o = { f2b(d0 * rstd * gg.x + bb.x), f2b(d1 * rstd * gg.y + bb.y),
                  f2b(d2 * rstd * gg.z + bb.z), f2b(d3 * rstd * gg.w + bb.w) };
    ((ushort4*)(OUT + (size_t)row * C))[lane] = o;
}

// ---------------------------------------------------------------- 64x64 GEMM
// BK=64, 4 waves, dbuf LDS via gload_lds w16 (wave-uniform LDS base),
// XOR swizzle (rule #21): inverse-swizzled global src chunk + swizzled ds_read.
template<int K, int MODE>
DEV void gemm_body(const unsigned short* __restrict__ A, int m0,
                   const unsigned short* __restrict__ BTt,
                   const float* __restrict__ biast,
                   const float* __restrict__ res, void* __restrict__ outp,
                   int ldo, int ocol0,
                   unsigned short (&As)[2][4096], unsigned short (&Bs)[2][4096])
{
    constexpr int BK = 64, NKT = K / BK;
    const int tid  = threadIdx.x;
    const int lane = tid & 63, wid = tid >> 6;
    const int srow = tid >> 3;                    // 0..31
    const int schk = (tid & 7) ^ (srow & 7);      // inverse-swizzled src chunk

    const unsigned short* Ag = A   + (size_t)(m0 + srow) * K + schk * 8;
    const unsigned short* Bg = BTt + (size_t)srow        * K + schk * 8;

    const int wbase = __builtin_amdgcn_readfirstlane(wid) * 512;

    gload16(Ag,          &As[0][wbase]);
    gload16(Ag + 32 * K, &As[0][wbase + 2048]);
    gload16(Bg,          &Bs[0][wbase]);
    gload16(Bg + 32 * K, &Bs[0][wbase + 2048]);
    __syncthreads();

    f32x4 acc[4] = {};
    const int lr = lane & 15, lk = lane >> 4;
    const int sw = lr & 7;

    for (int kt = 0; kt < NKT; ++kt) {
        if (kt + 1 < NKT) {
            const int nb = (kt + 1) & 1;
            gload16(Ag + (kt + 1) * BK,          &As[nb][wbase]);
            gload16(Ag + 32 * K + (kt + 1) * BK, &As[nb][wbase + 2048]);
            gload16(Bg + (kt + 1) * BK,          &Bs[nb][wbase]);
            gload16(Bg + 32 * K + (kt + 1) * BK, &Bs[nb][wbase + 2048]);
        }
        const unsigned short* as = As[kt & 1];
        const unsigned short* bs = Bs[kt & 1];
        #pragma unroll
        for (int s = 0; s < 2; ++s) {
            const int c16 = (s * 4 + lk) ^ sw;
            bf16x8 bfr = *reinterpret_cast<const bf16x8*>(&bs[(wid * 16 + lr) * 64 + c16 * 8]);
            #pragma unroll
            for (int m = 0; m < 4; ++m) {
                bf16x8 afr = *reinterpret_cast<const bf16x8*>(&as[(m * 16 + lr) * 64 + c16 * 8]);
                acc[m] = __builtin_amdgcn_mfma_f32_16x16x32_bf16(afr, bfr, acc[m], 0, 0, 0);
            }
        }
        if (kt + 1 < NKT) __syncthreads();
    }

    const int col  = ocol0 + wid * 16 + lr;
    const float bcol = biast[wid * 16 + lr];
    #pragma unroll
    for (int m = 0; m < 4; ++m) {
        #pragma unroll
        for (int r = 0; r < 4; ++r) {
            const int row = m0 + m * 16 + lk * 4 + r;
            float v = acc[m][r] + bcol;
            if (MODE == 0) {
                ((unsigned short*)outp)[(size_t)row * ldo + col] = f2b(v);
            } else if (MODE == 1) {
                ((unsigned short*)outp)[(size_t)row * ldo + col] = f2b(gelu_f(v));
            } else {
                v += res[(size_t)row * ldo + col];
                ((float*)outp)[(size_t)row * ldo + col] = v;
            }
        }
    }
}

// XCD-swizzled 1D-grid tile map, column-fastest (T1). Requires nwg % 8 == 0.
template<int NC, int TS>
DEV void tile_map(int& m0, int& n0){
    const int nwg = gridDim.x;
    const int lin = blockIdx.x;
    const int tile = (lin & 7) * (nwg >> 3) + (lin >> 3);
    m0 = (tile / NC) * TS;
    n0 = (tile % NC) * TS;
}

// Fused Q/K/V GEMM: N=768 packed output, A = tn for Q cols, xb for K/V cols.
__global__ __launch_bounds__(256)
void qkv_kernel(const unsigned short* __restrict__ tn,
                const unsigned short* __restrict__ xb,
                const unsigned short* __restrict__ WT,    // [768][256]
                const float* __restrict__ bqkv,           // [768]
                unsigned short* __restrict__ QKV)         // [8192][768]
{
    __shared__ unsigned short As[2][4096], Bs[2][4096];
    int m0, n0; tile_map<12, 64>(m0, n0);
    const unsigned short* A = (n0 < 256) ? tn : xb;
    gemm_body<256, 0>(A, m0, WT + (size_t)n0 * 256,
                      bqkv + n0, nullptr, QKV, 768, n0, As, Bs);
}

template<int K, int MODE, int NC>
__global__ __launch_bounds__(256)
void gemm_kernel(const unsigned short* __restrict__ A,
                 const unsigned short* __restrict__ BT,
                 const float* __restrict__ bias,
                 const float* __restrict__ res,
                 void* __restrict__ outp, int ldo)
{
    __shared__ unsigned short As[2][4096], Bs[2][4096];
    int m0, n0; tile_map<NC, 64>(m0, n0);
    gemm_body<K, MODE>(A, m0, BT + (size_t)n0 * K,
                       bias + n0, res, outp, ldo, n0, As, Bs);
}

// ---------------------------------------------------------------- attention
// Thread = (voxel, head): full 32-channel head owned in registers.
// NO cross-lane ops (the old 3x shfl/neighbor = ds_bpermute = LDS-pipe floor),
// NO branches (invalid neighbors read a safe row; -inf score -> p = 0).
// Wave = 8 voxels x 8 heads; 8 lanes of a voxel read 512 contiguous bytes.
// QKV layout: [NROW][768] bf16: Q (pre-scaled) 0..255, K 256..511, V 512..767.
DEV float dot8(unsigned int x, unsigned int y, unsigned int z, unsigned int w,
               const float* q, float s){
    s = fmaf(q[0], blo(x), s); s = fmaf(q[1], bhi(x), s);
    s = fmaf(q[2], blo(y), s); s = fmaf(q[3], bhi(y), s);
    s = fmaf(q[4], blo(z), s); s = fmaf(q[5], bhi(z), s);
    s = fmaf(q[6], blo(w), s); s = fmaf(q[7], bhi(w), s);
    return s;
}
DEV void pv8(unsigned int x, unsigned int y, unsigned int z, unsigned int w,
             float p, float* a){
    a[0] = fmaf(p, blo(x), a[0]); a[1] = fmaf(p, bhi(x), a[1]);
    a[2] = fmaf(p, blo(y), a[2]); a[3] = fmaf(p, bhi(y), a[3]);
    a[4] = fmaf(p, blo(z), a[4]); a[5] = fmaf(p, bhi(z), a[5]);
    a[6] = fmaf(p, blo(w), a[6]); a[7] = fmaf(p, bhi(w), a[7]);
}

__global__ __launch_bounds__(256, 1)
void attn_kernel(const unsigned short* __restrict__ QKV,
                 unsigned short* __restrict__ AO)
{
    const int t    = blockIdx.x * 256 + threadIdx.x;
    const int vox  = t >> 3;
    const int head = t & 7;
    const int d = (vox >> 8) & 15, h = (vox >> 4) & 15, w = vox & 15;
    const int ch = head * 32;

    float q[32];
    {
        const uint4* qp = reinterpret_cast<const uint4*>(&QKV[(size_t)vox * 768 + ch]);
        uint4 u0 = qp[0], u1 = qp[1], u2 = qp[2], u3 = qp[3];
        q[0]=blo(u0.x); q[1]=bhi(u0.x); q[2]=blo(u0.y); q[3]=bhi(u0.y);
        q[4]=blo(u0.z); q[5]=bhi(u0.z); q[6]=blo(u0.w); q[7]=bhi(u0.w);
        q[8]=blo(u1.x); q[9]=bhi(u1.x); q[10]=blo(u1.y); q[11]=bhi(u1.y);
        q[12]=blo(u1.z); q[13]=bhi(u1.z); q[14]=blo(u1.w); q[15]=bhi(u1.w);
        q[16]=blo(u2.x); q[17]=bhi(u2.x); q[18]=blo(u2.y); q[19]=bhi(u2.y);
        q[20]=blo(u2.z); q[21]=bhi(u2.z); q[22]=blo(u2.w); q[23]=bhi(u2.w);
        q[24]=blo(u3.x); q[25]=bhi(u3.x); q[26]=blo(u3.y); q[27]=bhi(u3.y);
        q[28]=blo(u3.z); q[29]=bhi(u3.z); q[30]=blo(u3.w); q[31]=bhi(u3.w);
    }

    float sc[27];
    int   nr[27];
    #pragma unroll
    for (int kk = 0; kk < 27; ++kk) {
        const int di = kk / 9 - 1, hi2 = (kk / 3) % 3 - 1, wi = kk % 3 - 1;
        const int nd = d + di, nh = h + hi2, nw = w + wi;
        const bool valid = (kk != 13) && ((unsigned)nd < 16u) &&
                           ((unsigned)nh < 16u) && ((unsigned)nw < 16u);
        const int r = valid ? ((vox & 4096) | (nd << 8) | (nh << 4) | nw) : vox;
        nr[kk] = r;
        const uint4* kp = reinterpret_cast<const uint4*>(&QKV[(size_t)r * 768 + 256 + ch]);
        uint4 u0 = kp[0], u1 = kp[1], u2 = kp[2], u3 = kp[3];
        float s = 0.0f;
        s = dot8(u0.x, u0.y, u0.z, u0.w, q + 0,  s);
        s = dot8(u1.x, u1.y, u1.z, u1.w, q + 8,  s);
        s = dot8(u2.x, u2.y, u2.z, u2.w, q + 16, s);
        s = dot8(u3.x, u3.y, u3.z, u3.w, q + 24, s);
        sc[kk] = valid ? s : -INFINITY;
    }

    float mx = sc[0];
    #pragma unroll
    for (int kk = 1; kk < 27; ++kk) mx = fmaxf(mx, sc[kk]);
    float z = 0.0f;
    #pragma unroll
    for (int kk = 0; kk < 27; ++kk) { float p = __expf(sc[kk] - mx); sc[kk] = p; z += p; }
    const float inv = 1.0f / z;

    float acc[32] = {};
    #pragma unroll
    for (int kk = 0; kk < 27; ++kk) {
        const uint4* vp = reinterpret_cast<const uint4*>(&QKV[(size_t)nr[kk] * 768 + 512 + ch]);
        uint4 u0 = vp[0], u1 = vp[1], u2 = vp[2], u3 = vp[3];
        const float p = sc[kk];
        pv8(u0.x, u0.y, u0.z, u0.w, p, acc + 0);
        pv8(u1.x, u1.y, u1.z, u1.w, p, acc + 8);
        pv8(u2.x, u2.y, u2.z, u2.w, p, acc + 16);
        pv8(u3.x, u3.y, u3.z, u3.w, p, acc + 24);
    }

    uint4* op = reinterpret_cast<uint4*>(&AO[(size_t)vox * C + ch]);
    #pragma unroll
    for (int i = 0; i < 4; ++i) {
        uint4 o;
        o.x = (unsigned)f2b(acc[i*8+0] * inv) | ((unsigned)f2b(acc[i*8+1] * inv) << 16);
        o.y = (unsigned)f2b(acc[i*8+2] * inv) | ((unsigned)f2b(acc[i*8+3] * inv) << 16);
        o.z = (unsigned)f2b(acc[i*8+4] * inv) | ((unsigned)f2b(acc[i*8+5] * inv) << 16);
        o.w = (unsigned)f2b(acc[i*8+6] * inv) | ((unsigned)f2b(acc[i*8+7] * inv) << 16);
        op[i] = o;
    }
}

// ---------------------------------------------------------------- launch
extern "C" void kernel_launch(void* const* d_in, const int* in_sizes, int n_in,
                              void* d_out, int out_size, void* d_ws, size_t ws_size,
                              hipStream_t stream)
{
    const float* x   = (const float*)d_in[0];
    const float* Wq  = (const float*)d_in[1];
    const float* bq  = (const float*)d_in[2];
    const float* Wk  = (const float*)d_in[3];
    const float* bk  = (const float*)d_in[4];
    const float* Wv  = (const float*)d_in[5];
    const float* bv  = (const float*)d_in[6];
    const float* Wo  = (const float*)d_in[7];
    const float* bo  = (const float*)d_in[8];
    const float* g1  = (const float*)d_in[9];
    const float* b1  = (const float*)d_in[10];
    const float* g2  = (const float*)d_in[11];
    const float* b2  = (const float*)d_in[12];
    const float* W1  = (const float*)d_in[13];
    const float* bf1 = (const float*)d_in[14];
    const float* W2  = (const float*)d_in[15];
    const float* bf2 = (const float*)d_in[16];

    char* ws = (char*)d_ws;
    size_t o = 0;
    unsigned short* WQT = (unsigned short*)(ws + o); o += (size_t)256 * 256 * 2;   // [768][256] with WKT/WVT
    unsigned short* WKT = (unsigned short*)(ws + o); o += (size_t)256 * 256 * 2;
    unsigned short* WVT = (unsigned short*)(ws + o); o += (size_t)256 * 256 * 2;
    unsigned short* WOT = (unsigned short*)(ws + o); o += (size_t)256 * 256 * 2;
    unsigned short* W1T = (unsigned short*)(ws + o); o += (size_t)256 * 1024 * 2;
    unsigned short* W2T = (unsigned short*)(ws + o); o += (size_t)1024 * 256 * 2;
    float*          bqkv= (float*)(ws + o);          o += (size_t)768 * 4;
    unsigned short* tn  = (unsigned short*)(ws + o); o += (size_t)NROW * C * 2;
    unsigned short* xb  = (unsigned short*)(ws + o); o += (size_t)NROW * C * 2;
    unsigned short* QKVb= (unsigned short*)(ws + o); o += (size_t)NROW * 768 * 2;
    unsigned short* AOb = (unsigned short*)(ws + o); o += (size_t)NROW * C * 2;
    float*          Tf  = (float*)(ws + o);          o += (size_t)NROW * C * 4;
    unsigned short* tn2 = (unsigned short*)(ws + o); o += (size_t)NROW * C * 2;
    unsigned short* Hb  = (unsigned short*)(ws + o); o += (size_t)NROW * F * 2;

    prep_ln_kernel<<<193 + NROW / 4, 256, 0, stream>>>(Wq, Wk, Wv, Wo, W1, W2, bq, bk, bv,
                                                       WQT, WKT, WVT, WOT, W1T, W2T, bqkv,
                                                       x, g1, b1, tn, xb);

    qkv_kernel<<<(NROW / 64) * 12, 256, 0, stream>>>(tn, xb, WQT, bqkv, QKVb);

    attn_kernel<<<NROW * 8 / 256, 256, 0, stream>>>(QKVb, AOb);

    gemm_kernel<256, 2, 4><<<(NROW / 64) * 4, 256, 0, stream>>>(AOb, WOT, bo, x, Tf, 256);

    ln_kernel<<<NROW / 4, 256, 0, stream>>>(Tf, g2, b2, tn2);

    gemm_kernel<256, 1, 16><<<(NROW / 64) * 16, 256, 0, stream>>>(tn2, W1T, bf1, nullptr, Hb, 1024);

    gemm_kernel<1024, 2, 4><<<(NROW / 64) * 4, 256, 0, stream>>>(Hb, W2T, bf2, Tf, (float*)d_out, 256);
}